// Round 1
// baseline (646.343 us; speedup 1.0000x reference)
//
#include <hip/hip_runtime.h>

// Problem constants (fixed by setup_inputs)
#define B_ROWS 4096   // latents
#define N_CLUST 1024  // codebook entries
#define KDIM 4096     // C*L = 64*64

#define EMA_OLD 0.01f
#define EMA_NEW 0.99f

// ---------------- workspace layout ----------------
// best   : u64[B_ROWS]   @ 0        (packed (d2_bits<<32)|col, atomicMin)
// yy     : f32[B_ROWS]   @ 32768    (||y_b||^2)
// mm     : f32[N_CLUST]  @ 49152    (||m_j||^2)
// winner : i32[N_CLUST]  @ 53248    (max b assigned to cluster, -1 if none)
#define WS_BEST_OFF   0
#define WS_YY_OFF     (B_ROWS * 8)
#define WS_MM_OFF     (WS_YY_OFF + B_ROWS * 4)
#define WS_WINNER_OFF (WS_MM_OFF + N_CLUST * 4)

__global__ void init_ws(unsigned long long* __restrict__ best,
                        int* __restrict__ winner) {
    int i = blockIdx.x * blockDim.x + threadIdx.x;
    if (i < B_ROWS) best[i] = 0xFFFFFFFFFFFFFFFFull;
    if (i < N_CLUST) winner[i] = -1;
}

// one wave (64 lanes) per row: out[r] = sum(x[r][:]^2)
__global__ void rowsumsq(const float* __restrict__ x,
                         float* __restrict__ out, int rows) {
    int wave = (blockIdx.x * blockDim.x + threadIdx.x) >> 6;
    int lane = threadIdx.x & 63;
    if (wave >= rows) return;
    const float4* xp = (const float4*)(x + (size_t)wave * KDIM);
    float s = 0.f;
    for (int i = lane; i < KDIM / 4; i += 64) {
        float4 v = xp[i];
        s += v.x * v.x + v.y * v.y + v.z * v.z + v.w * v.w;
    }
    for (int off = 32; off > 0; off >>= 1) s += __shfl_down(s, off, 64);
    if (lane == 0) out[wave] = s;
}

// Tiled fp32 distance + fused argmin.
// C[b,j] = yy[b] - 2*dot(Y[b],M[j]) + mm[j]; per-row argmin merged via
// packed-u64 atomicMin (positive floats: bit order == value order;
// low 32 bits = col -> ties resolve to smallest j like np.argmin).
#define BM 128
#define BN 64
#define BK 16

__global__ __launch_bounds__(256) void dist_argmin(
    const float* __restrict__ Y, const float* __restrict__ M,
    const float* __restrict__ yy, const float* __restrict__ mm,
    unsigned long long* __restrict__ best) {
    __shared__ float As[BK][BM + 4];
    __shared__ float Bs[BK][BN + 4];
    __shared__ unsigned long long red[BM];

    const int t = threadIdx.x;
    const int row0 = blockIdx.x * BM;
    const int col0 = blockIdx.y * BN;

    // staging: 4 threads per row along K, one float4 each
    const int srow = t >> 2;          // 0..63
    const int skc  = (t & 3) << 2;    // 0,4,8,12

    // micro-tile: 8 rows x 4 cols per thread
    const int tx = t & 15;            // col group
    const int ty = t >> 4;            // row group

    const float* aptr0 = Y + (size_t)(row0 + srow) * KDIM + skc;
    const float* aptr1 = Y + (size_t)(row0 + srow + 64) * KDIM + skc;
    const float* bptr  = M + (size_t)(col0 + srow) * KDIM + skc;

    float acc[8][4];
#pragma unroll
    for (int i = 0; i < 8; ++i)
#pragma unroll
        for (int j = 0; j < 4; ++j) acc[i][j] = 0.f;

    for (int k0 = 0; k0 < KDIM; k0 += BK) {
        float4 a0 = *(const float4*)(aptr0 + k0);
        float4 a1 = *(const float4*)(aptr1 + k0);
        float4 bv = *(const float4*)(bptr + k0);
        __syncthreads();  // previous compute done before overwrite
        As[skc + 0][srow] = a0.x;
        As[skc + 1][srow] = a0.y;
        As[skc + 2][srow] = a0.z;
        As[skc + 3][srow] = a0.w;
        As[skc + 0][srow + 64] = a1.x;
        As[skc + 1][srow + 64] = a1.y;
        As[skc + 2][srow + 64] = a1.z;
        As[skc + 3][srow + 64] = a1.w;
        Bs[skc + 0][srow] = bv.x;
        Bs[skc + 1][srow] = bv.y;
        Bs[skc + 2][srow] = bv.z;
        Bs[skc + 3][srow] = bv.w;
        __syncthreads();
#pragma unroll
        for (int k = 0; k < BK; ++k) {
            float4 ar0 = *(const float4*)&As[k][ty * 8];
            float4 ar1 = *(const float4*)&As[k][ty * 8 + 4];
            float4 br  = *(const float4*)&Bs[k][tx * 4];
            const float a[8] = {ar0.x, ar0.y, ar0.z, ar0.w,
                                ar1.x, ar1.y, ar1.z, ar1.w};
            const float b[4] = {br.x, br.y, br.z, br.w};
#pragma unroll
            for (int i = 0; i < 8; ++i)
#pragma unroll
                for (int j = 0; j < 4; ++j) acc[i][j] += a[i] * b[j];
        }
    }

    // ---- fused argmin epilogue ----
    __syncthreads();
    if (t < BM) red[t] = 0xFFFFFFFFFFFFFFFFull;
    if (t + 128 < BM) red[t + 128] = 0xFFFFFFFFFFFFFFFFull;
    __syncthreads();
#pragma unroll
    for (int i = 0; i < 8; ++i) {
        int lr = ty * 8 + i;
        float yv = yy[row0 + lr];
#pragma unroll
        for (int j = 0; j < 4; ++j) {
            int gc = col0 + tx * 4 + j;
            float d2 = yv - 2.0f * acc[i][j] + mm[gc];
            unsigned long long key =
                ((unsigned long long)__float_as_uint(d2) << 32) |
                (unsigned int)gc;
            atomicMin(&red[lr], key);
        }
    }
    __syncthreads();
    if (t < BM) atomicMin(&best[row0 + t], red[t]);
}

// winner[z] = max b with z_b == z  (last-write-wins scatter semantics)
__global__ void pick_winner(const unsigned long long* __restrict__ best,
                            int* __restrict__ winner) {
    int b = blockIdx.x * blockDim.x + threadIdx.x;
    if (b < B_ROWS) {
        int z = (int)(unsigned int)(best[b] & 0xFFFFFFFFull);
        atomicMax(&winner[z], b);
    }
}

// out[idx]        = new_m  = m*0.01 + y[w]*0.99          (or m if untouched)
// out[n+idx]      = new_sd = (new_m - y[w])^2*0.01 + sd*0.99  (or sd)
__global__ __launch_bounds__(256) void write_out(
    const float* __restrict__ y, const float* __restrict__ m,
    const float* __restrict__ sd, const int* __restrict__ winner,
    float* __restrict__ out) {
    const int idx = blockIdx.x;
    const int t = threadIdx.x;
    const int w = winner[idx];
    const float4* mp = (const float4*)(m + (size_t)idx * KDIM);
    const float4* sp = (const float4*)(sd + (size_t)idx * KDIM);
    float4* om = (float4*)(out + (size_t)idx * KDIM);
    float4* os = (float4*)(out + (size_t)(N_CLUST + idx) * KDIM);
    if (w >= 0) {
        const float4* yp = (const float4*)(y + (size_t)w * KDIM);
        for (int i = t; i < KDIM / 4; i += 256) {
            float4 mv = mp[i], yv = yp[i], sv = sp[i];
            float4 nm, ns;
            nm.x = mv.x * EMA_OLD + yv.x * EMA_NEW;
            nm.y = mv.y * EMA_OLD + yv.y * EMA_NEW;
            nm.z = mv.z * EMA_OLD + yv.z * EMA_NEW;
            nm.w = mv.w * EMA_OLD + yv.w * EMA_NEW;
            float dx = nm.x - yv.x, dy = nm.y - yv.y;
            float dz = nm.z - yv.z, dw = nm.w - yv.w;
            ns.x = dx * dx * EMA_OLD + sv.x * EMA_NEW;
            ns.y = dy * dy * EMA_OLD + sv.y * EMA_NEW;
            ns.z = dz * dz * EMA_OLD + sv.z * EMA_NEW;
            ns.w = dw * dw * EMA_OLD + sv.w * EMA_NEW;
            om[i] = nm;
            os[i] = ns;
        }
    } else {
        for (int i = t; i < KDIM / 4; i += 256) {
            om[i] = mp[i];
            os[i] = sp[i];
        }
    }
}

extern "C" void kernel_launch(void* const* d_in, const int* in_sizes, int n_in,
                              void* d_out, int out_size, void* d_ws,
                              size_t ws_size, hipStream_t stream) {
    const float* y  = (const float*)d_in[0];  // [4096, 64, 64]
    const float* m  = (const float*)d_in[1];  // [1024, 64, 64]
    const float* sd = (const float*)d_in[2];  // [1024, 64, 64]
    // d_in[3] = p, unused by the reference output
    float* out = (float*)d_out;

    char* ws = (char*)d_ws;
    unsigned long long* best = (unsigned long long*)(ws + WS_BEST_OFF);
    float* yy   = (float*)(ws + WS_YY_OFF);
    float* mm   = (float*)(ws + WS_MM_OFF);
    int* winner = (int*)(ws + WS_WINNER_OFF);

    init_ws<<<(B_ROWS + 255) / 256, 256, 0, stream>>>(best, winner);
    rowsumsq<<<B_ROWS * 64 / 256, 256, 0, stream>>>(y, yy, B_ROWS);
    rowsumsq<<<N_CLUST * 64 / 256, 256, 0, stream>>>(m, mm, N_CLUST);

    dim3 grid(B_ROWS / BM, N_CLUST / BN);
    dist_argmin<<<grid, 256, 0, stream>>>(y, m, yy, mm, best);

    pick_winner<<<B_ROWS / 256, 256, 0, stream>>>(best, winner);
    write_out<<<N_CLUST, 256, 0, stream>>>(y, m, sd, winner, out);
}

// Round 2
// 302.706 us; speedup vs baseline: 2.1352x; 2.1352x over previous
//
#include <hip/hip_runtime.h>

#define B_ROWS 4096
#define N_CLUST 1024
#define KDIM 4096
#define KT 64          // k-tiles of 64

#define EMA_OLD 0.01f
#define EMA_NEW 0.99f

typedef unsigned short ushortT;
typedef _Float16 half8 __attribute__((ext_vector_type(8)));
typedef float f32x16 __attribute__((ext_vector_type(16)));

// ---------------- workspace layout (bytes) ----------------
#define WS_BEST_OFF   0                      // u64[4096]   32768
#define WS_YY_OFF     32768                  // f32[4096]   16384
#define WS_MM_OFF     49152                  // f32[1024]    4096
#define WS_WINNER_OFF 53248                  // i32[1024]    4096
#define WS_YHI_OFF    65536                  // f16 tiled   33554432
#define WS_YLO_OFF    (WS_YHI_OFF + 33554432)
#define WS_MHI_OFF    (WS_YLO_OFF + 33554432)
#define WS_MLO_OFF    (WS_MHI_OFF + 8388608)
#define WS_REQUIRED   (WS_MLO_OFF + 8388608)  // ~84.2 MB

__global__ void init_ws(unsigned long long* __restrict__ best,
                        int* __restrict__ winner) {
    int i = blockIdx.x * blockDim.x + threadIdx.x;
    if (i < B_ROWS) best[i] = 0xFFFFFFFFFFFFFFFFull;
    if (i < N_CLUST) winner[i] = -1;
}

// one wave per row: out[r] = sum(x[r][:]^2)
__global__ void rowsumsq(const float* __restrict__ x,
                         float* __restrict__ out, int rows) {
    int wave = (blockIdx.x * blockDim.x + threadIdx.x) >> 6;
    int lane = threadIdx.x & 63;
    if (wave >= rows) return;
    const float4* xp = (const float4*)(x + (size_t)wave * KDIM);
    float s = 0.f;
    for (int i = lane; i < KDIM / 4; i += 64) {
        float4 v = xp[i];
        s += v.x * v.x + v.y * v.y + v.z * v.z + v.w * v.w;
    }
    for (int off = 32; off > 0; off >>= 1) s += __shfl_down(s, off, 64);
    if (lane == 0) out[wave] = s;
}

// ---------------- f16 hi/lo split into tiled+swizzled layout ----------------
// Tiled layout: block (rb, kt) of RB rows x 64 halfs, contiguous.
// Within a row, 16B chunk at logical pos c stored at physical p = c ^ (r&7).
// One thread per 16B output chunk (8 elements).
__global__ void convert_split(const float* __restrict__ src,
                              ushortT* __restrict__ hi,
                              ushortT* __restrict__ lo,
                              int nchunks, int rb_shift) {
    int cid = blockIdx.x * blockDim.x + threadIdx.x;
    if (cid >= nchunks) return;
    int row = cid >> 9;          // 512 chunks per row (4096/8)
    int ci  = cid & 511;
    int kt  = ci >> 3;
    int p   = ci & 7;            // physical chunk within 128B row segment
    int r   = row & ((1 << rb_shift) - 1);
    int rb  = row >> rb_shift;
    int c   = p ^ (r & 7);       // logical chunk
    const float* s = src + ((size_t)row << 12) + kt * 64 + c * 8;
    float4 v0 = *(const float4*)s;
    float4 v1 = *(const float4*)(s + 4);
    float vv[8] = {v0.x, v0.y, v0.z, v0.w, v1.x, v1.y, v1.z, v1.w};
    half8 hv, lv;
#pragma unroll
    for (int i = 0; i < 8; ++i) {
        _Float16 h = (_Float16)vv[i];
        hv[i] = h;
        lv[i] = (_Float16)(vv[i] - (float)h);
    }
    size_t off = ((size_t)rb * KT + kt) * ((size_t)(1 << rb_shift) * 64)
               + (size_t)r * 64 + p * 8;
    *(half8*)(hi + off) = hv;
    *(half8*)(lo + off) = lv;
}

// ---------------- MFMA distance + fused argmin ----------------
__device__ __forceinline__ void gload_lds16(const void* g, void* l) {
    __builtin_amdgcn_global_load_lds(
        (const __attribute__((address_space(1))) unsigned int*)g,
        (__attribute__((address_space(3))) unsigned int*)l, 16, 0, 0);
}

__device__ __forceinline__ half8 ldfrag(const ushortT* s, int r, int c) {
    int p = c ^ (r & 7);
    return *(const half8*)(s + r * 64 + p * 8);
}

// block tile 128 rows x 64 cols, BK=64; 4 waves each 64x32 (two 32x32 mfma tiles)
__global__ __launch_bounds__(256, 2) void dist_argmin_mfma(
    const ushortT* __restrict__ Ah, const ushortT* __restrict__ Al,
    const ushortT* __restrict__ Bh, const ushortT* __restrict__ Bl,
    const float* __restrict__ yy, const float* __restrict__ mm,
    unsigned long long* __restrict__ best) {
    __shared__ __align__(16) ushortT sAh[128 * 64], sAl[128 * 64];
    __shared__ __align__(16) ushortT sBh[64 * 64], sBl[64 * 64];
    __shared__ unsigned long long red[128];

    const int t = threadIdx.x;
    const int w = t >> 6, l = t & 63;
    const int row0 = blockIdx.x * 128, col0 = blockIdx.y * 64;
    const int wr = (w >> 1) * 64, wc = (w & 1) * 32;
    const int m0 = l & 31, hsel = l >> 5;

    if (t < 128) red[t] = 0xFFFFFFFFFFFFFFFFull;

    const char* gAh = (const char*)Ah + (size_t)blockIdx.x * (KT * 16384) + l * 16;
    const char* gAl = (const char*)Al + (size_t)blockIdx.x * (KT * 16384) + l * 16;
    const char* gBh = (const char*)Bh + (size_t)blockIdx.y * (KT * 8192) + l * 16;
    const char* gBl = (const char*)Bl + (size_t)blockIdx.y * (KT * 8192) + l * 16;

    f32x16 acc0, acc1;
#pragma unroll
    for (int i = 0; i < 16; ++i) { acc0[i] = 0.f; acc1[i] = 0.f; }

    for (int kt = 0; kt < KT; ++kt) {
        __syncthreads();   // previous tile fully consumed
#pragma unroll
        for (int j = 0; j < 4; ++j) {
            int ch = w * 4 + j;
            gload_lds16(gAh + (size_t)kt * 16384 + ch * 1024, (char*)sAh + ch * 1024);
            gload_lds16(gAl + (size_t)kt * 16384 + ch * 1024, (char*)sAl + ch * 1024);
        }
#pragma unroll
        for (int j = 0; j < 2; ++j) {
            int ch = w * 2 + j;
            gload_lds16(gBh + (size_t)kt * 8192 + ch * 1024, (char*)sBh + ch * 1024);
            gload_lds16(gBl + (size_t)kt * 8192 + ch * 1024, (char*)sBl + ch * 1024);
        }
        __syncthreads();   // drains vmcnt -> LDS tile ready
#pragma unroll
        for (int kk = 0; kk < 4; ++kk) {
            int c = kk * 2 + hsel;
            half8 ah0 = ldfrag(sAh, wr + m0, c);
            half8 al0 = ldfrag(sAl, wr + m0, c);
            half8 ah1 = ldfrag(sAh, wr + 32 + m0, c);
            half8 al1 = ldfrag(sAl, wr + 32 + m0, c);
            half8 bh  = ldfrag(sBh, wc + m0, c);
            half8 bl  = ldfrag(sBl, wc + m0, c);
            acc0 = __builtin_amdgcn_mfma_f32_32x32x16_f16(ah0, bh, acc0, 0, 0, 0);
            acc1 = __builtin_amdgcn_mfma_f32_32x32x16_f16(ah1, bh, acc1, 0, 0, 0);
            acc0 = __builtin_amdgcn_mfma_f32_32x32x16_f16(ah0, bl, acc0, 0, 0, 0);
            acc1 = __builtin_amdgcn_mfma_f32_32x32x16_f16(ah1, bl, acc1, 0, 0, 0);
            acc0 = __builtin_amdgcn_mfma_f32_32x32x16_f16(al0, bh, acc0, 0, 0, 0);
            acc1 = __builtin_amdgcn_mfma_f32_32x32x16_f16(al1, bh, acc1, 0, 0, 0);
        }
    }

    __syncthreads();
    const int gcol = col0 + wc + m0;
    const float mmv = mm[gcol];
#pragma unroll
    for (int r = 0; r < 16; ++r) {
        int ri = (r & 3) + 8 * (r >> 2) + 4 * hsel;  // row within 32x32 tile
        {
            int lr = wr + ri;
            float d2 = yy[row0 + lr] - 2.0f * acc0[r] + mmv;
            unsigned long long key =
                ((unsigned long long)__float_as_uint(d2) << 32) | (unsigned)gcol;
            atomicMin(&red[lr], key);
        }
        {
            int lr = wr + 32 + ri;
            float d2 = yy[row0 + lr] - 2.0f * acc1[r] + mmv;
            unsigned long long key =
                ((unsigned long long)__float_as_uint(d2) << 32) | (unsigned)gcol;
            atomicMin(&red[lr], key);
        }
    }
    __syncthreads();
    if (t < 128) atomicMin(&best[row0 + t], red[t]);
}

// ---------------- fp32 fallback (round-1 kernel) ----------------
#define BM 128
#define BN 64
#define BK 16

__global__ __launch_bounds__(256) void dist_argmin_fp32(
    const float* __restrict__ Y, const float* __restrict__ M,
    const float* __restrict__ yy, const float* __restrict__ mm,
    unsigned long long* __restrict__ best) {
    __shared__ float As[BK][BM + 4];
    __shared__ float Bs[BK][BN + 4];
    __shared__ unsigned long long red[BM];

    const int t = threadIdx.x;
    const int row0 = blockIdx.x * BM;
    const int col0 = blockIdx.y * BN;
    const int srow = t >> 2;
    const int skc  = (t & 3) << 2;
    const int tx = t & 15;
    const int ty = t >> 4;

    const float* aptr0 = Y + (size_t)(row0 + srow) * KDIM + skc;
    const float* aptr1 = Y + (size_t)(row0 + srow + 64) * KDIM + skc;
    const float* bptr  = M + (size_t)(col0 + srow) * KDIM + skc;

    float acc[8][4];
#pragma unroll
    for (int i = 0; i < 8; ++i)
#pragma unroll
        for (int j = 0; j < 4; ++j) acc[i][j] = 0.f;

    for (int k0 = 0; k0 < KDIM; k0 += BK) {
        float4 a0 = *(const float4*)(aptr0 + k0);
        float4 a1 = *(const float4*)(aptr1 + k0);
        float4 bv = *(const float4*)(bptr + k0);
        __syncthreads();
        As[skc + 0][srow] = a0.x; As[skc + 1][srow] = a0.y;
        As[skc + 2][srow] = a0.z; As[skc + 3][srow] = a0.w;
        As[skc + 0][srow + 64] = a1.x; As[skc + 1][srow + 64] = a1.y;
        As[skc + 2][srow + 64] = a1.z; As[skc + 3][srow + 64] = a1.w;
        Bs[skc + 0][srow] = bv.x; Bs[skc + 1][srow] = bv.y;
        Bs[skc + 2][srow] = bv.z; Bs[skc + 3][srow] = bv.w;
        __syncthreads();
#pragma unroll
        for (int k = 0; k < BK; ++k) {
            float4 ar0 = *(const float4*)&As[k][ty * 8];
            float4 ar1 = *(const float4*)&As[k][ty * 8 + 4];
            float4 br  = *(const float4*)&Bs[k][tx * 4];
            const float a[8] = {ar0.x, ar0.y, ar0.z, ar0.w,
                                ar1.x, ar1.y, ar1.z, ar1.w};
            const float b[4] = {br.x, br.y, br.z, br.w};
#pragma unroll
            for (int i = 0; i < 8; ++i)
#pragma unroll
                for (int j = 0; j < 4; ++j) acc[i][j] += a[i] * b[j];
        }
    }
    __syncthreads();
    if (t < BM) red[t] = 0xFFFFFFFFFFFFFFFFull;
    if (t + 128 < BM) red[t + 128] = 0xFFFFFFFFFFFFFFFFull;
    __syncthreads();
#pragma unroll
    for (int i = 0; i < 8; ++i) {
        int lr = ty * 8 + i;
        float yv = yy[row0 + lr];
#pragma unroll
        for (int j = 0; j < 4; ++j) {
            int gc = col0 + tx * 4 + j;
            float d2 = yv - 2.0f * acc[i][j] + mm[gc];
            unsigned long long key =
                ((unsigned long long)__float_as_uint(d2) << 32) | (unsigned)gc;
            atomicMin(&red[lr], key);
        }
    }
    __syncthreads();
    if (t < BM) atomicMin(&best[row0 + t], red[t]);
}

// ---------------- scatter + output ----------------
__global__ void pick_winner(const unsigned long long* __restrict__ best,
                            int* __restrict__ winner) {
    int b = blockIdx.x * blockDim.x + threadIdx.x;
    if (b < B_ROWS) {
        int z = (int)(unsigned int)(best[b] & 0xFFFFFFFFull);
        atomicMax(&winner[z], b);
    }
}

__global__ __launch_bounds__(256) void write_out(
    const float* __restrict__ y, const float* __restrict__ m,
    const float* __restrict__ sd, const int* __restrict__ winner,
    float* __restrict__ out) {
    const int idx = blockIdx.x;
    const int t = threadIdx.x;
    const int w = winner[idx];
    const float4* mp = (const float4*)(m + (size_t)idx * KDIM);
    const float4* sp = (const float4*)(sd + (size_t)idx * KDIM);
    float4* om = (float4*)(out + (size_t)idx * KDIM);
    float4* os = (float4*)(out + (size_t)(N_CLUST + idx) * KDIM);
    if (w >= 0) {
        const float4* yp = (const float4*)(y + (size_t)w * KDIM);
        for (int i = t; i < KDIM / 4; i += 256) {
            float4 mv = mp[i], yv = yp[i], sv = sp[i];
            float4 nm, ns;
            nm.x = mv.x * EMA_OLD + yv.x * EMA_NEW;
            nm.y = mv.y * EMA_OLD + yv.y * EMA_NEW;
            nm.z = mv.z * EMA_OLD + yv.z * EMA_NEW;
            nm.w = mv.w * EMA_OLD + yv.w * EMA_NEW;
            float dx = nm.x - yv.x, dy = nm.y - yv.y;
            float dz = nm.z - yv.z, dw = nm.w - yv.w;
            ns.x = dx * dx * EMA_OLD + sv.x * EMA_NEW;
            ns.y = dy * dy * EMA_OLD + sv.y * EMA_NEW;
            ns.z = dz * dz * EMA_OLD + sv.z * EMA_NEW;
            ns.w = dw * dw * EMA_OLD + sv.w * EMA_NEW;
            om[i] = nm;
            os[i] = ns;
        }
    } else {
        for (int i = t; i < KDIM / 4; i += 256) {
            om[i] = mp[i];
            os[i] = sp[i];
        }
    }
}

extern "C" void kernel_launch(void* const* d_in, const int* in_sizes, int n_in,
                              void* d_out, int out_size, void* d_ws,
                              size_t ws_size, hipStream_t stream) {
    const float* y  = (const float*)d_in[0];
    const float* m  = (const float*)d_in[1];
    const float* sd = (const float*)d_in[2];
    float* out = (float*)d_out;

    char* ws = (char*)d_ws;
    unsigned long long* best = (unsigned long long*)(ws + WS_BEST_OFF);
    float* yy   = (float*)(ws + WS_YY_OFF);
    float* mm   = (float*)(ws + WS_MM_OFF);
    int* winner = (int*)(ws + WS_WINNER_OFF);

    init_ws<<<(B_ROWS + 255) / 256, 256, 0, stream>>>(best, winner);
    rowsumsq<<<B_ROWS * 64 / 256, 256, 0, stream>>>(y, yy, B_ROWS);
    rowsumsq<<<N_CLUST * 64 / 256, 256, 0, stream>>>(m, mm, N_CLUST);

    if (ws_size >= (size_t)WS_REQUIRED) {
        ushortT* yhi = (ushortT*)(ws + WS_YHI_OFF);
        ushortT* ylo = (ushortT*)(ws + WS_YLO_OFF);
        ushortT* mhi = (ushortT*)(ws + WS_MHI_OFF);
        ushortT* mlo = (ushortT*)(ws + WS_MLO_OFF);

        int ychunks = B_ROWS * (KDIM / 8);   // 2,097,152
        int mchunks = N_CLUST * (KDIM / 8);  //   524,288
        convert_split<<<ychunks / 256, 256, 0, stream>>>(y, yhi, ylo, ychunks, 7);
        convert_split<<<mchunks / 256, 256, 0, stream>>>(m, mhi, mlo, mchunks, 6);

        dim3 grid(B_ROWS / 128, N_CLUST / 64);
        dist_argmin_mfma<<<grid, 256, 0, stream>>>(yhi, ylo, mhi, mlo, yy, mm, best);
    } else {
        dim3 grid(B_ROWS / BM, N_CLUST / BN);
        dist_argmin_fp32<<<grid, 256, 0, stream>>>(y, m, yy, mm, best);
    }

    pick_winner<<<B_ROWS / 256, 256, 0, stream>>>(best, winner);
    write_out<<<N_CLUST, 256, 0, stream>>>(y, m, sd, winner, out);
}

// Round 3
// 298.147 us; speedup vs baseline: 2.1679x; 1.0153x over previous
//
#include <hip/hip_runtime.h>

#define B_ROWS 4096
#define N_CLUST 1024
#define KDIM 4096
#define KT 64          // k-tiles of 64

#define EMA_OLD 0.01f
#define EMA_NEW 0.99f

typedef unsigned short ushortT;
typedef _Float16 half8 __attribute__((ext_vector_type(8)));
typedef float f32x16 __attribute__((ext_vector_type(16)));

// ---------------- workspace layout (bytes) ----------------
// best[4096] u64 @0, winner[1024] i32 @32768  -> one 0xFF memset (36864 B)
#define WS_BEST_OFF   0
#define WS_WINNER_OFF 32768
#define WS_YY_OFF     36864
#define WS_MM_OFF     53248
#define WS_YHI_OFF    65536
#define WS_YLO_OFF    (WS_YHI_OFF + 33554432)
#define WS_MHI_OFF    (WS_YLO_OFF + 33554432)
#define WS_MLO_OFF    (WS_MHI_OFF + 8388608)
#define WS_REQUIRED   (WS_MLO_OFF + 8388608)  // ~84.2 MB

// one wave per row: out[r] = sum(x[r][:]^2)   (bit-identical to round 2)
__global__ void rowsumsq(const float* __restrict__ x,
                         float* __restrict__ out, int rows) {
    int wave = (blockIdx.x * blockDim.x + threadIdx.x) >> 6;
    int lane = threadIdx.x & 63;
    if (wave >= rows) return;
    const float4* xp = (const float4*)(x + (size_t)wave * KDIM);
    float s = 0.f;
    for (int i = lane; i < KDIM / 4; i += 64) {
        float4 v = xp[i];
        s += v.x * v.x + v.y * v.y + v.z * v.z + v.w * v.w;
    }
    for (int off = 32; off > 0; off >>= 1) s += __shfl_down(s, off, 64);
    if (lane == 0) out[wave] = s;
}

// ---------------- f16 hi/lo split into tiled+swizzled layout ----------------
// (bit-identical to round 2)
__global__ void convert_split(const float* __restrict__ src,
                              ushortT* __restrict__ hi,
                              ushortT* __restrict__ lo,
                              int nchunks, int rb_shift) {
    int cid = blockIdx.x * blockDim.x + threadIdx.x;
    if (cid >= nchunks) return;
    int row = cid >> 9;          // 512 chunks per row (4096/8)
    int ci  = cid & 511;
    int kt  = ci >> 3;
    int p   = ci & 7;
    int r   = row & ((1 << rb_shift) - 1);
    int rb  = row >> rb_shift;
    int c   = p ^ (r & 7);
    const float* s = src + ((size_t)row << 12) + kt * 64 + c * 8;
    float4 v0 = *(const float4*)s;
    float4 v1 = *(const float4*)(s + 4);
    float vv[8] = {v0.x, v0.y, v0.z, v0.w, v1.x, v1.y, v1.z, v1.w};
    half8 hv, lv;
#pragma unroll
    for (int i = 0; i < 8; ++i) {
        _Float16 h = (_Float16)vv[i];
        hv[i] = h;
        lv[i] = (_Float16)(vv[i] - (float)h);
    }
    size_t off = ((size_t)rb * KT + kt) * ((size_t)(1 << rb_shift) * 64)
               + (size_t)r * 64 + p * 8;
    *(half8*)(hi + off) = hv;
    *(half8*)(lo + off) = lv;
}

// ---------------- MFMA distance + fused argmin ----------------
__device__ __forceinline__ void gload_lds16(const void* g, void* l) {
    __builtin_amdgcn_global_load_lds(
        (const __attribute__((address_space(1))) unsigned int*)g,
        (__attribute__((address_space(3))) unsigned int*)l, 16, 0, 0);
}

__device__ __forceinline__ half8 ldfrag(const ushortT* s, int r, int c) {
    int p = c ^ (r & 7);
    return *(const half8*)(s + r * 64 + p * 8);
}

#define MFMA_HH(a, b, c) __builtin_amdgcn_mfma_f32_32x32x16_f16(a, b, c, 0, 0, 0)

// Block tile 128 rows x 64 cols, BK=64. 4 waves:
//   wave w: row-half rh=w&1 (rows rh*64..rh*64+63, all 64 cols),
//           k-half  kh=w>>1 (kk in {2kh, 2kh+1}).
// 64x64 wave tile (2x2 of 32x32) -> 8 frag reads per 12 MFMAs.
// kh=1 partials merged into kh=0 accs through LDS (reusing A-stage region).
__global__ __launch_bounds__(256, 2) void dist_argmin_mfma(
    const ushortT* __restrict__ Ah, const ushortT* __restrict__ Al,
    const ushortT* __restrict__ Bh, const ushortT* __restrict__ Bl,
    const float* __restrict__ yy, const float* __restrict__ mm,
    unsigned long long* __restrict__ best) {
    __shared__ __align__(16) char smem[50176];
    ushortT* sAh = (ushortT*)smem;               // 16384 B
    ushortT* sAl = (ushortT*)(smem + 16384);     // 16384 B
    ushortT* sBh = (ushortT*)(smem + 32768);     //  8192 B
    ushortT* sBl = (ushortT*)(smem + 40960);     //  8192 B
    unsigned long long* red = (unsigned long long*)(smem + 49152);  // 1024 B
    float* part = (float*)smem;                  // reused after K-loop (32 KB)

    const int t = threadIdx.x;
    const int w = t >> 6, l = t & 63;
    const int row0 = blockIdx.x * 128, col0 = blockIdx.y * 64;
    const int rh = w & 1;          // row half
    const int kh = w >> 1;         // k half
    const int wr = rh * 64;
    const int m0 = l & 31, hsel = l >> 5;

    if (t < 128) red[t] = 0xFFFFFFFFFFFFFFFFull;

    const char* gAh = (const char*)Ah + (size_t)blockIdx.x * (KT * 16384) + l * 16;
    const char* gAl = (const char*)Al + (size_t)blockIdx.x * (KT * 16384) + l * 16;
    const char* gBh = (const char*)Bh + (size_t)blockIdx.y * (KT * 8192) + l * 16;
    const char* gBl = (const char*)Bl + (size_t)blockIdx.y * (KT * 8192) + l * 16;

    f32x16 acc00, acc01, acc10, acc11;
#pragma unroll
    for (int i = 0; i < 16; ++i) {
        acc00[i] = 0.f; acc01[i] = 0.f; acc10[i] = 0.f; acc11[i] = 0.f;
    }

    for (int kt = 0; kt < KT; ++kt) {
        __syncthreads();   // previous tile fully consumed
#pragma unroll
        for (int j = 0; j < 4; ++j) {
            int ch = w * 4 + j;
            gload_lds16(gAh + (size_t)kt * 16384 + ch * 1024, smem + ch * 1024);
            gload_lds16(gAl + (size_t)kt * 16384 + ch * 1024, smem + 16384 + ch * 1024);
        }
#pragma unroll
        for (int j = 0; j < 2; ++j) {
            int ch = w * 2 + j;
            gload_lds16(gBh + (size_t)kt * 8192 + ch * 1024, smem + 32768 + ch * 1024);
            gload_lds16(gBl + (size_t)kt * 8192 + ch * 1024, smem + 40960 + ch * 1024);
        }
        __syncthreads();   // LDS tile ready
#pragma unroll
        for (int kk2 = 0; kk2 < 2; ++kk2) {
            int c = (kh * 2 + kk2) * 2 + hsel;
            half8 ah0 = ldfrag(sAh, wr + m0, c);
            half8 ah1 = ldfrag(sAh, wr + 32 + m0, c);
            half8 al0 = ldfrag(sAl, wr + m0, c);
            half8 al1 = ldfrag(sAl, wr + 32 + m0, c);
            half8 bh0 = ldfrag(sBh, m0, c);
            half8 bh1 = ldfrag(sBh, 32 + m0, c);
            half8 bl0 = ldfrag(sBl, m0, c);
            half8 bl1 = ldfrag(sBl, 32 + m0, c);
            // per-accumulator order: hh, hl, lh (matches round 2 exactly)
            acc00 = MFMA_HH(ah0, bh0, acc00);
            acc01 = MFMA_HH(ah0, bh1, acc01);
            acc10 = MFMA_HH(ah1, bh0, acc10);
            acc11 = MFMA_HH(ah1, bh1, acc11);
            acc00 = MFMA_HH(ah0, bl0, acc00);
            acc01 = MFMA_HH(ah0, bl1, acc01);
            acc10 = MFMA_HH(ah1, bl0, acc10);
            acc11 = MFMA_HH(ah1, bl1, acc11);
            acc00 = MFMA_HH(al0, bh0, acc00);
            acc01 = MFMA_HH(al0, bh1, acc01);
            acc10 = MFMA_HH(al1, bh0, acc10);
            acc11 = MFMA_HH(al1, bh1, acc11);
        }
    }

    __syncthreads();  // all compute done before reusing A-stage LDS
    if (kh == 1) {
        // layout per rh: [tile(4)][reg4(4)][lane(64)] float4 -> conflict-free
        float* p = part + rh * 4096;
#pragma unroll
        for (int g = 0; g < 4; ++g) {
            *(float4*)(p + 0 * 1024 + g * 256 + l * 4) =
                make_float4(acc00[g * 4], acc00[g * 4 + 1], acc00[g * 4 + 2], acc00[g * 4 + 3]);
            *(float4*)(p + 1 * 1024 + g * 256 + l * 4) =
                make_float4(acc01[g * 4], acc01[g * 4 + 1], acc01[g * 4 + 2], acc01[g * 4 + 3]);
            *(float4*)(p + 2 * 1024 + g * 256 + l * 4) =
                make_float4(acc10[g * 4], acc10[g * 4 + 1], acc10[g * 4 + 2], acc10[g * 4 + 3]);
            *(float4*)(p + 3 * 1024 + g * 256 + l * 4) =
                make_float4(acc11[g * 4], acc11[g * 4 + 1], acc11[g * 4 + 2], acc11[g * 4 + 3]);
        }
    }
    __syncthreads();
    if (kh == 0) {
        const float* p = part + rh * 4096;
#pragma unroll
        for (int g = 0; g < 4; ++g) {
            float4 v0 = *(const float4*)(p + 0 * 1024 + g * 256 + l * 4);
            float4 v1 = *(const float4*)(p + 1 * 1024 + g * 256 + l * 4);
            float4 v2 = *(const float4*)(p + 2 * 1024 + g * 256 + l * 4);
            float4 v3 = *(const float4*)(p + 3 * 1024 + g * 256 + l * 4);
            acc00[g * 4] += v0.x; acc00[g * 4 + 1] += v0.y;
            acc00[g * 4 + 2] += v0.z; acc00[g * 4 + 3] += v0.w;
            acc01[g * 4] += v1.x; acc01[g * 4 + 1] += v1.y;
            acc01[g * 4 + 2] += v1.z; acc01[g * 4 + 3] += v1.w;
            acc10[g * 4] += v2.x; acc10[g * 4 + 1] += v2.y;
            acc10[g * 4 + 2] += v2.z; acc10[g * 4 + 3] += v2.w;
            acc11[g * 4] += v3.x; acc11[g * 4 + 1] += v3.y;
            acc11[g * 4 + 2] += v3.z; acc11[g * 4 + 3] += v3.w;
        }
        // ---- argmin epilogue (same arithmetic as round 2) ----
        const float mmv0 = mm[col0 + m0];
        const float mmv1 = mm[col0 + 32 + m0];
#pragma unroll
        for (int r = 0; r < 16; ++r) {
            int ri = (r & 3) + 8 * (r >> 2) + 4 * hsel;
            {
                int lr = wr + ri;
                float d2 = yy[row0 + lr] - 2.0f * acc00[r] + mmv0;
                atomicMin(&red[lr],
                          ((unsigned long long)__float_as_uint(d2) << 32) |
                              (unsigned)(col0 + m0));
                float d2b = yy[row0 + lr] - 2.0f * acc01[r] + mmv1;
                atomicMin(&red[lr],
                          ((unsigned long long)__float_as_uint(d2b) << 32) |
                              (unsigned)(col0 + 32 + m0));
            }
            {
                int lr = wr + 32 + ri;
                float d2 = yy[row0 + lr] - 2.0f * acc10[r] + mmv0;
                atomicMin(&red[lr],
                          ((unsigned long long)__float_as_uint(d2) << 32) |
                              (unsigned)(col0 + m0));
                float d2b = yy[row0 + lr] - 2.0f * acc11[r] + mmv1;
                atomicMin(&red[lr],
                          ((unsigned long long)__float_as_uint(d2b) << 32) |
                              (unsigned)(col0 + 32 + m0));
            }
        }
    }
    __syncthreads();
    if (t < 128) atomicMin(&best[row0 + t], red[t]);
}

// ---------------- fp32 fallback ----------------
#define BM 128
#define BN 64
#define BK 16

__global__ __launch_bounds__(256) void dist_argmin_fp32(
    const float* __restrict__ Y, const float* __restrict__ M,
    const float* __restrict__ yy, const float* __restrict__ mm,
    unsigned long long* __restrict__ best) {
    __shared__ float As[BK][BM + 4];
    __shared__ float Bs[BK][BN + 4];
    __shared__ unsigned long long red[BM];

    const int t = threadIdx.x;
    const int row0 = blockIdx.x * BM;
    const int col0 = blockIdx.y * BN;
    const int srow = t >> 2;
    const int skc  = (t & 3) << 2;
    const int tx = t & 15;
    const int ty = t >> 4;

    const float* aptr0 = Y + (size_t)(row0 + srow) * KDIM + skc;
    const float* aptr1 = Y + (size_t)(row0 + srow + 64) * KDIM + skc;
    const float* bptr  = M + (size_t)(col0 + srow) * KDIM + skc;

    float acc[8][4];
#pragma unroll
    for (int i = 0; i < 8; ++i)
#pragma unroll
        for (int j = 0; j < 4; ++j) acc[i][j] = 0.f;

    for (int k0 = 0; k0 < KDIM; k0 += BK) {
        float4 a0 = *(const float4*)(aptr0 + k0);
        float4 a1 = *(const float4*)(aptr1 + k0);
        float4 bv = *(const float4*)(bptr + k0);
        __syncthreads();
        As[skc + 0][srow] = a0.x; As[skc + 1][srow] = a0.y;
        As[skc + 2][srow] = a0.z; As[skc + 3][srow] = a0.w;
        As[skc + 0][srow + 64] = a1.x; As[skc + 1][srow + 64] = a1.y;
        As[skc + 2][srow + 64] = a1.z; As[skc + 3][srow + 64] = a1.w;
        Bs[skc + 0][srow] = bv.x; Bs[skc + 1][srow] = bv.y;
        Bs[skc + 2][srow] = bv.z; Bs[skc + 3][srow] = bv.w;
        __syncthreads();
#pragma unroll
        for (int k = 0; k < BK; ++k) {
            float4 ar0 = *(const float4*)&As[k][ty * 8];
            float4 ar1 = *(const float4*)&As[k][ty * 8 + 4];
            float4 br  = *(const float4*)&Bs[k][tx * 4];
            const float a[8] = {ar0.x, ar0.y, ar0.z, ar0.w,
                                ar1.x, ar1.y, ar1.z, ar1.w};
            const float b[4] = {br.x, br.y, br.z, br.w};
#pragma unroll
            for (int i = 0; i < 8; ++i)
#pragma unroll
                for (int j = 0; j < 4; ++j) acc[i][j] += a[i] * b[j];
        }
    }
    __syncthreads();
    if (t < BM) red[t] = 0xFFFFFFFFFFFFFFFFull;
    if (t + 128 < BM) red[t + 128] = 0xFFFFFFFFFFFFFFFFull;
    __syncthreads();
#pragma unroll
    for (int i = 0; i < 8; ++i) {
        int lr = ty * 8 + i;
        float yv = yy[row0 + lr];
#pragma unroll
        for (int j = 0; j < 4; ++j) {
            int gc = col0 + tx * 4 + j;
            float d2 = yv - 2.0f * acc[i][j] + mm[gc];
            unsigned long long key =
                ((unsigned long long)__float_as_uint(d2) << 32) | (unsigned)gc;
            atomicMin(&red[lr], key);
        }
    }
    __syncthreads();
    if (t < BM) atomicMin(&best[row0 + t], red[t]);
}

// ---------------- scatter + output ----------------
__global__ void pick_winner(const unsigned long long* __restrict__ best,
                            int* __restrict__ winner) {
    int b = blockIdx.x * blockDim.x + threadIdx.x;
    if (b < B_ROWS) {
        int z = (int)(unsigned int)(best[b] & 0xFFFFFFFFull);
        atomicMax(&winner[z], b);
    }
}

__global__ __launch_bounds__(256) void write_out(
    const float* __restrict__ y, const float* __restrict__ m,
    const float* __restrict__ sd, const int* __restrict__ winner,
    float* __restrict__ out) {
    const int idx = blockIdx.x;
    const int t = threadIdx.x;
    const int w = winner[idx];
    const float4* mp = (const float4*)(m + (size_t)idx * KDIM);
    const float4* sp = (const float4*)(sd + (size_t)idx * KDIM);
    float4* om = (float4*)(out + (size_t)idx * KDIM);
    float4* os = (float4*)(out + (size_t)(N_CLUST + idx) * KDIM);
    if (w >= 0) {
        const float4* yp = (const float4*)(y + (size_t)w * KDIM);
        for (int i = t; i < KDIM / 4; i += 256) {
            float4 mv = mp[i], yv = yp[i], sv = sp[i];
            float4 nm, ns;
            nm.x = mv.x * EMA_OLD + yv.x * EMA_NEW;
            nm.y = mv.y * EMA_OLD + yv.y * EMA_NEW;
            nm.z = mv.z * EMA_OLD + yv.z * EMA_NEW;
            nm.w = mv.w * EMA_OLD + yv.w * EMA_NEW;
            float dx = nm.x - yv.x, dy = nm.y - yv.y;
            float dz = nm.z - yv.z, dw = nm.w - yv.w;
            ns.x = dx * dx * EMA_OLD + sv.x * EMA_NEW;
            ns.y = dy * dy * EMA_OLD + sv.y * EMA_NEW;
            ns.z = dz * dz * EMA_OLD + sv.z * EMA_NEW;
            ns.w = dw * dw * EMA_OLD + sv.w * EMA_NEW;
            om[i] = nm;
            os[i] = ns;
        }
    } else {
        for (int i = t; i < KDIM / 4; i += 256) {
            om[i] = mp[i];
            os[i] = sp[i];
        }
    }
}

extern "C" void kernel_launch(void* const* d_in, const int* in_sizes, int n_in,
                              void* d_out, int out_size, void* d_ws,
                              size_t ws_size, hipStream_t stream) {
    const float* y  = (const float*)d_in[0];
    const float* m  = (const float*)d_in[1];
    const float* sd = (const float*)d_in[2];
    float* out = (float*)d_out;

    char* ws = (char*)d_ws;
    unsigned long long* best = (unsigned long long*)(ws + WS_BEST_OFF);
    int* winner = (int*)(ws + WS_WINNER_OFF);
    float* yy   = (float*)(ws + WS_YY_OFF);
    float* mm   = (float*)(ws + WS_MM_OFF);

    // best = u64 max, winner = -1, in one async memset (graph-capture safe)
    hipMemsetAsync(ws, 0xFF, 36864, stream);

    rowsumsq<<<B_ROWS * 64 / 256, 256, 0, stream>>>(y, yy, B_ROWS);
    rowsumsq<<<N_CLUST * 64 / 256, 256, 0, stream>>>(m, mm, N_CLUST);

    if (ws_size >= (size_t)WS_REQUIRED) {
        ushortT* yhi = (ushortT*)(ws + WS_YHI_OFF);
        ushortT* ylo = (ushortT*)(ws + WS_YLO_OFF);
        ushortT* mhi = (ushortT*)(ws + WS_MHI_OFF);
        ushortT* mlo = (ushortT*)(ws + WS_MLO_OFF);

        int ychunks = B_ROWS * (KDIM / 8);
        int mchunks = N_CLUST * (KDIM / 8);
        convert_split<<<ychunks / 256, 256, 0, stream>>>(y, yhi, ylo, ychunks, 7);
        convert_split<<<mchunks / 256, 256, 0, stream>>>(m, mhi, mlo, mchunks, 6);

        dim3 grid(B_ROWS / 128, N_CLUST / 64);
        dist_argmin_mfma<<<grid, 256, 0, stream>>>(yhi, ylo, mhi, mlo, yy, mm, best);
    } else {
        dim3 grid(B_ROWS / BM, N_CLUST / BN);
        dist_argmin_fp32<<<grid, 256, 0, stream>>>(y, m, yy, mm, best);
    }

    pick_winner<<<B_ROWS / 256, 256, 0, stream>>>(best, winner);
    write_out<<<N_CLUST, 256, 0, stream>>>(y, m, sd, winner, out);
}